// Round 11
// baseline (2530.409 us; speedup 1.0000x reference)
//
#include <hip/hip_runtime.h>
#include <math.h>

typedef __attribute__((ext_vector_type(8))) short bf16x8;
typedef __attribute__((ext_vector_type(4))) float f32x4;
typedef __attribute__((ext_vector_type(2))) float f32x2;

static __device__ __forceinline__ unsigned short f2bf(float f) {
  unsigned u = __float_as_uint(f);
  unsigned r = (u + 0x7FFF + ((u >> 16) & 1)) >> 16; // RNE
  return (unsigned short)r;
}
static __device__ __forceinline__ float bf2f(unsigned short b) {
  return __uint_as_float(((unsigned)b) << 16);
}

#define DPP_ADD(x, ctrl) \
  ((x) + __int_as_float(__builtin_amdgcn_update_dpp(0, __float_as_int(x), (ctrl), 0xf, 0xf, false)))

#define NSHARD 64
#define GRIDB 1024

struct Params {
  const float* x;
  const int* esrc; const int* edst; const int* batch;
  const float* W0; const float* W1; const float* W2;
  const float* W3; const float* W4; const float* W5;
  const float* att0; const float* att1; const float* att2;
  const float* bia0; const float* bia1; const float* bia2;
  const float* gam0; const float* gam1; const float* gam2;
  const float* bet0; const float* bet1; const float* bet2;
  const float* Wmu; const float* bmu; const float* Wlv; const float* blv;
  float* out;
  unsigned short* wt; unsigned short* xlb; unsigned short* xrb;
  float* hA; float* hB; float* gat; float* bnsums; float* pool;
  int* deg; int* rowptr; int* cursor; int* bs; int* colb; int* bar;
  int N, E, G, nbN, ntiles, nbGat;
  float inv_n;
};

// -------- device-wide barrier: monotonic counter, agent scope --------
// Co-residency guaranteed: grid == 1024 == 4 blocks/CU * 256 CUs, enforced by
// __launch_bounds__(256,4) (VGPR<=128) and 28.2 KB LDS (<=40 KB/block).
static __device__ __forceinline__ void gsync(int* bar) {
  __syncthreads();
  if (threadIdx.x == 0) {
    int a = __hip_atomic_fetch_add(bar, 1, __ATOMIC_ACQ_REL, __HIP_MEMORY_SCOPE_AGENT);
    int target = (a / GRIDB + 1) * GRIDB;
    while (__hip_atomic_load(bar, __ATOMIC_ACQUIRE, __HIP_MEMORY_SCOPE_AGENT) < target) {
      __builtin_amdgcn_s_sleep(2);
    }
  }
  __syncthreads();
}

// -------- MFMA dual GEMM phase (quadrant blocks) + fused BN/GELU/resid --------
// q = blockIdx&3: mat = q>>1 (0=L,1=R), panel = q&1 (cols 0-127 / 128-255).
// B panel staged once; tiles grid-strided with stride gridDim/4.
static __device__ void mm_phase(const Params& P,
                                const float* src, const float* bnsums,
                                const float* g, const float* be,
                                const float* resid, float* hout,
                                const unsigned short* wtL,
                                unsigned short (*Ah)[72], unsigned short (*Al)[72],
                                unsigned short (*B)[72], float* stat) {
  const int t = threadIdx.x;
  const int q = blockIdx.x & 3;
  const int mat = q >> 1, coff = (q & 1) * 128;
  const unsigned short* wb = wtL + mat * 16384 + coff * 64;
  unsigned short* dst = mat ? P.xrb : P.xlb;
  const int N = P.N;

#pragma unroll
  for (int j = 0; j < 4; ++j) {
    int cidx = t + 256 * j; // 1024 chunks of 8 shorts = 128 cols x 64 k
    int n = cidx >> 3, k0 = (cidx & 7) * 8;
    *(bf16x8*)&B[n][k0] = *(const bf16x8*)(wb + (size_t)n * 64 + k0);
  }

  const int wave = t >> 6, lane = t & 63;
  const int rw = (wave & 1) * 16, cw = (wave >> 1) * 64;
  const int m15 = lane & 15, quad = lane >> 4;
  const int arow = t >> 3, ac0 = (t & 7) * 8;

  float scale[8], shift[8];
  if (bnsums) {
    if (t < 128) {
      float a = 0.f;
      for (int sd = 0; sd < NSHARD; ++sd) a += bnsums[sd * 128 + t];
      stat[t] = a;
    }
    __syncthreads();
#pragma unroll
    for (int i = 0; i < 8; ++i) {
      int c = ac0 + i;
      float mu = stat[c] * P.inv_n;
      float var = stat[64 + c] * P.inv_n - mu * mu;
      float rs = rsqrtf(var + 1e-5f) * g[c];
      scale[i] = rs;
      shift[i] = be[c] - mu * rs;
    }
  }
  const bool wr_h = (hout != nullptr) && (q == 0);

  for (int tile = blockIdx.x >> 2; tile < P.ntiles; tile += gridDim.x >> 2) {
    int r0 = tile * 32;
    {
      int gr = r0 + arow;
      float vs[8] = {0.f, 0.f, 0.f, 0.f, 0.f, 0.f, 0.f, 0.f};
      if (gr < N) {
        float4 v0 = *(const float4*)(src + (size_t)gr * 64 + ac0);
        float4 v1 = *(const float4*)(src + (size_t)gr * 64 + ac0 + 4);
        vs[0] = v0.x; vs[1] = v0.y; vs[2] = v0.z; vs[3] = v0.w;
        vs[4] = v1.x; vs[5] = v1.y; vs[6] = v1.z; vs[7] = v1.w;
        if (bnsums) {
          float rv[8] = {0.f, 0.f, 0.f, 0.f, 0.f, 0.f, 0.f, 0.f};
          if (resid) {
            float4 r0v = *(const float4*)(resid + (size_t)gr * 64 + ac0);
            float4 r1v = *(const float4*)(resid + (size_t)gr * 64 + ac0 + 4);
            rv[0] = r0v.x; rv[1] = r0v.y; rv[2] = r0v.z; rv[3] = r0v.w;
            rv[4] = r1v.x; rv[5] = r1v.y; rv[6] = r1v.z; rv[7] = r1v.w;
          }
#pragma unroll
          for (int i = 0; i < 8; ++i) {
            float v = fmaf(vs[i], scale[i], shift[i]);
            float ge = 0.5f * v * (1.f + erff(v * 0.70710678118654752f));
            vs[i] = ge + rv[i];
          }
          if (wr_h) {
            float4 o0 = {vs[0], vs[1], vs[2], vs[3]};
            float4 o1 = {vs[4], vs[5], vs[6], vs[7]};
            *(float4*)(hout + (size_t)gr * 64 + ac0) = o0;
            *(float4*)(hout + (size_t)gr * 64 + ac0 + 4) = o1;
          }
        }
      }
      bf16x8 hi8, lo8;
#pragma unroll
      for (int i = 0; i < 8; ++i) {
        unsigned short hh = f2bf(vs[i]);
        hi8[i] = (short)hh;
        lo8[i] = (short)f2bf(vs[i] - bf2f(hh));
      }
      *(bf16x8*)&Ah[arow][ac0] = hi8;
      *(bf16x8*)&Al[arow][ac0] = lo8;
    }
    __syncthreads();

    f32x4 acc[4];
#pragma unroll
    for (int s = 0; s < 4; ++s) acc[s] = (f32x4){0.f, 0.f, 0.f, 0.f};
#pragma unroll
    for (int kk = 0; kk < 64; kk += 32) {
      bf16x8 ah = *(const bf16x8*)&Ah[rw + m15][kk + quad * 8];
      bf16x8 al = *(const bf16x8*)&Al[rw + m15][kk + quad * 8];
#pragma unroll
      for (int s = 0; s < 4; ++s) {
        bf16x8 b = *(const bf16x8*)&B[cw + s * 16 + m15][kk + quad * 8];
        acc[s] = __builtin_amdgcn_mfma_f32_16x16x32_bf16(ah, b, acc[s], 0, 0, 0);
        acc[s] = __builtin_amdgcn_mfma_f32_16x16x32_bf16(al, b, acc[s], 0, 0, 0);
      }
    }
#pragma unroll
    for (int s = 0; s < 4; ++s) {
#pragma unroll
      for (int r = 0; r < 4; ++r) {
        int row_g = r0 + rw + quad * 4 + r;
        if (row_g < N)
          dst[(size_t)row_g * 256 + coff + cw + s * 16 + m15] = f2bf(acc[s][r]);
      }
    }
    __syncthreads();
  }
}

// -------- GATv2 phase: wave/node, self-shift, depth-8 pipeline, sharded stats --------
static __device__ void gat_phase(const Params& P,
                                 const float* att, const float* bias,
                                 float* out, float* bnsums,
                                 float (*sres)[64]) {
  const int lane = threadIdx.x & 63;
  const int wv = threadIdx.x >> 6;
  const int N = P.N;
  const int* rowptr = P.rowptr;
  const int* colb = P.colb;
  float4 a4 = *(const float4*)(att + lane * 4);
  const float LOG2E = 1.4426950408889634f;
  const f32x2 a01 = {a4.x * LOG2E, a4.y * LOG2E};
  const f32x2 a23 = {a4.z * LOG2E, a4.w * LOG2E};
  const f32x2 c02 = {0.2f, 0.2f};
  const char* base = (const char*)P.xlb + (size_t)lane * 8;

  for (int ng = blockIdx.x; ng < P.nbGat; ng += gridDim.x) {
    const int node0 = ng * 4 + wv;
    const bool valid = node0 < N;
    const int node = __builtin_amdgcn_readfirstlane(valid ? node0 : 0);
    const int beg = rowptr[node];
    const int end = valid ? rowptr[node + 1] : beg;

    int o0 = colb[beg], o1 = colb[beg + 1], o2 = colb[beg + 2], o3 = colb[beg + 3];
    uint2 vbs = *(const uint2*)(base + (size_t)(unsigned)(node << 9));
    uint2 d0 = *(const uint2*)(base + (size_t)(unsigned)o0);
    uint2 d1 = *(const uint2*)(base + (size_t)(unsigned)o1);
    uint2 d2 = *(const uint2*)(base + (size_t)(unsigned)o2);
    uint2 d3 = *(const uint2*)(base + (size_t)(unsigned)o3);
    int p0 = colb[beg + 4], p1 = colb[beg + 5], p2 = colb[beg + 6], p3 = colb[beg + 7];
    uint2 t0 = *(const uint2*)(base + (size_t)(unsigned)p0);
    uint2 t1 = *(const uint2*)(base + (size_t)(unsigned)p1);
    uint2 t2 = *(const uint2*)(base + (size_t)(unsigned)p2);
    uint2 t3 = *(const uint2*)(base + (size_t)(unsigned)p3);
    int f0 = colb[beg + 8], f1 = colb[beg + 9], f2 = colb[beg + 10], f3 = colb[beg + 11];

    uint2 xru = *(const uint2*)((const char*)P.xrb + ((size_t)(unsigned)(node << 9)) + lane * 8);
    const f32x2 xr01 = {__uint_as_float(xru.x << 16), __uint_as_float(xru.x & 0xFFFF0000u)};
    const f32x2 xr23 = {__uint_as_float(xru.y << 16), __uint_as_float(xru.y & 0xFFFF0000u)};

    f32x2 sv01 = {__uint_as_float(vbs.x << 16), __uint_as_float(vbs.x & 0xFFFF0000u)};
    f32x2 sv23 = {__uint_as_float(vbs.y << 16), __uint_as_float(vbs.y & 0xFFFF0000u)};
    float m;
    {
      f32x2 s01 = sv01 + xr01;
      f32x2 s23 = sv23 + xr23;
      s01 = __builtin_elementwise_max(s01, s01 * c02);
      s23 = __builtin_elementwise_max(s23, s23 * c02);
      f32x2 qd = __builtin_elementwise_fma(s23, a23, s01 * a01);
      float p = qd.x + qd.y;
      p = DPP_ADD(p, 0xB1);
      p = DPP_ADD(p, 0x4E);
      p = DPP_ADD(p, 0x124);
      p = DPP_ADD(p, 0x128);
      m = p;
    }
    float lsum = 1.f;
    f32x2 o01 = sv01, o23 = sv23;

    auto proc = [&](uint2 vb, bool ok) {
      f32x2 v01 = {__uint_as_float(vb.x << 16), __uint_as_float(vb.x & 0xFFFF0000u)};
      f32x2 v23 = {__uint_as_float(vb.y << 16), __uint_as_float(vb.y & 0xFFFF0000u)};
      f32x2 s01 = v01 + xr01;
      f32x2 s23 = v23 + xr23;
      s01 = __builtin_elementwise_max(s01, s01 * c02);
      s23 = __builtin_elementwise_max(s23, s23 * c02);
      f32x2 qd = __builtin_elementwise_fma(s23, a23, s01 * a01);
      float p = qd.x + qd.y;
      p = DPP_ADD(p, 0xB1);
      p = DPP_ADD(p, 0x4E);
      p = DPP_ADD(p, 0x124);
      p = DPP_ADD(p, 0x128);
      float w = __builtin_amdgcn_exp2f(fminf(p - m, 126.f));
      w = ok ? w : 0.f;
      lsum += w;
      f32x2 w2 = {w, w};
      o01 = __builtin_elementwise_fma(w2, v01, o01);
      o23 = __builtin_elementwise_fma(w2, v23, o23);
    };

    for (int e = beg; e < end; e += 4) {
      uint2 u0 = *(const uint2*)(base + (size_t)(unsigned)f0);
      uint2 u1 = *(const uint2*)(base + (size_t)(unsigned)f1);
      uint2 u2 = *(const uint2*)(base + (size_t)(unsigned)f2);
      uint2 u3 = *(const uint2*)(base + (size_t)(unsigned)f3);
      f0 = colb[e + 12]; f1 = colb[e + 13]; f2 = colb[e + 14]; f3 = colb[e + 15];
      proc(d0, true);
      proc(d1, e + 1 < end);
      proc(d2, e + 2 < end);
      proc(d3, e + 3 < end);
      d0 = t0; d1 = t1; d2 = t2; d3 = t3;
      t0 = u0; t1 = u1; t2 = u2; t3 = u3;
    }

    float inv = __builtin_amdgcn_rcpf(lsum);
    float rx = o01.x * inv, ry = o01.y * inv, rz = o23.x * inv, rw2 = o23.y * inv;
    rx += __shfl_xor(rx, 16, 64); rx += __shfl_xor(rx, 32, 64);
    ry += __shfl_xor(ry, 16, 64); ry += __shfl_xor(ry, 32, 64);
    rz += __shfl_xor(rz, 16, 64); rz += __shfl_xor(rz, 32, 64);
    rw2 += __shfl_xor(rw2, 16, 64); rw2 += __shfl_xor(rw2, 32, 64);
    if (lane < 16) {
      float4 res = {0.f, 0.f, 0.f, 0.f};
      if (valid) {
        float4 b4 = *(const float4*)(bias + lane * 4);
        res.x = 0.25f * rx + b4.x;
        res.y = 0.25f * ry + b4.y;
        res.z = 0.25f * rz + b4.z;
        res.w = 0.25f * rw2 + b4.w;
        *(float4*)(out + (size_t)node * 64 + lane * 4) = res;
      }
      *(float4*)&sres[wv][lane * 4] = res;
    }
    __syncthreads();
    if (threadIdx.x < 64) {
      int c = threadIdx.x;
      float s0 = sres[0][c], s1 = sres[1][c], s2 = sres[2][c], s3 = sres[3][c];
      float* bsh = bnsums + (size_t)(ng & (NSHARD - 1)) * 128;
      atomicAdd(&bsh[c], s0 + s1 + s2 + s3);
      atomicAdd(&bsh[64 + c], s0 * s0 + s1 * s1 + s2 * s2 + s3 * s3);
    }
    __syncthreads();
  }
}

// -------- the mega-kernel --------
__global__ __launch_bounds__(256, 4) void k_mega(Params P) {
  __shared__ union {
    struct {
      unsigned short Ah[32][72];
      unsigned short Al[32][72];
      unsigned short B[128][72];
      float stat[128];
    } mm;
    int scan[256];
    float sres[4][64];
  } sh;
  __shared__ int boff;

  const int t = threadIdx.x;
  const int N = P.N, E = P.E;
  const int nbEu = (E + 255) / 256;

  // ---- P0: W transpose + degree atomics ----
  for (int u = blockIdx.x; u < 384 + nbEu; u += gridDim.x) {
    if (u < 384) {
      int gid = u * 256 + t;
      int m = gid >> 14, r = gid & 16383;
      int k = r >> 8, n = r & 255;
      const float* W = (m == 0) ? P.W0 : (m == 1) ? P.W1 : (m == 2) ? P.W2
                     : (m == 3) ? P.W3 : (m == 4) ? P.W4 : P.W5;
      P.wt[(size_t)m * 16384 + n * 64 + k] = f2bf(W[k * 256 + n]);
    } else {
      int e = (u - 384) * 256 + t;
      if (e < E) atomicAdd(&P.deg[P.edst[e]], 1);
    }
  }
  gsync(P.bar);

  // ---- P1: per-block scan of deg -> rowptr(partial), bs ----
  for (int u = blockIdx.x; u < P.nbN; u += gridDim.x) {
    int gid = u * 256 + t;
    int v = (gid < N) ? P.deg[gid] : 0;
    sh.scan[t] = v;
    __syncthreads();
    for (int off = 1; off < 256; off <<= 1) {
      int tv = (t >= off) ? sh.scan[t - off] : 0;
      __syncthreads();
      sh.scan[t] += tv;
      __syncthreads();
    }
    if (gid < N) P.rowptr[gid] = sh.scan[t] - v;
    if (t == 255) P.bs[u] = sh.scan[255];
    __syncthreads();
  }
  gsync(P.bar);

  // ---- P2: add block offsets (redundant bs scan per unit) ----
  for (int u = blockIdx.x; u < P.nbN; u += gridDim.x) {
    int v = (t < P.nbN) ? P.bs[t] : 0;
    sh.scan[t] = v;
    __syncthreads();
    for (int off = 1; off < 256; off <<= 1) {
      int tv = (t >= off) ? sh.scan[t - off] : 0;
      __syncthreads();
      sh.scan[t] += tv;
      __syncthreads();
    }
    if (t == u) boff = sh.scan[t] - v;
    __syncthreads();
    int gid = u * 256 + t;
    if (gid < N) {
      int val = P.rowptr[gid] + boff;
      P.rowptr[gid] = val;
      P.cursor[gid] = val;
    }
    if (gid == 0) P.rowptr[N] = E;
    if (u == 0 && t < 16) P.colb[E + t] = 0; // sentinels for depth-8 prefetch
    __syncthreads();
  }
  gsync(P.bar);

  // ---- P3: CSR fill + mm layer0 ----
  for (int e = blockIdx.x * 256 + t; e < E; e += gridDim.x * 256) {
    int p = atomicAdd(&P.cursor[P.edst[e]], 1);
    P.colb[p] = P.esrc[e] << 9;
  }
  mm_phase(P, P.x, nullptr, nullptr, nullptr, nullptr, nullptr,
           P.wt, sh.mm.Ah, sh.mm.Al, sh.mm.B, sh.mm.stat);
  gsync(P.bar);

  // ---- P4: gat layer0 ----
  gat_phase(P, P.att0, P.bia0, P.gat, P.bnsums, sh.sres);
  gsync(P.bar);

  // ---- P5: mm layer1 (applies h0 = gelu(bn0(gat0))) ----
  mm_phase(P, P.gat, P.bnsums, P.gam0, P.bet0, nullptr, P.hA,
           P.wt + 2 * 16384, sh.mm.Ah, sh.mm.Al, sh.mm.B, sh.mm.stat);
  gsync(P.bar);

  // ---- P6: gat layer1 ----
  gat_phase(P, P.att1, P.bia1, P.gat, P.bnsums + NSHARD * 128, sh.sres);
  gsync(P.bar);

  // ---- P7: mm layer2 (applies h1 = gelu(bn1(gat1)) + h0) ----
  mm_phase(P, P.gat, P.bnsums + NSHARD * 128, P.gam1, P.bet1, P.hA, P.hB,
           P.wt + 4 * 16384, sh.mm.Ah, sh.mm.Al, sh.mm.B, sh.mm.stat);
  gsync(P.bar);

  // ---- P8: gat layer2 ----
  gat_phase(P, P.att2, P.bia2, P.gat, P.bnsums + 2 * NSHARD * 128, sh.sres);
  gsync(P.bar);

  // ---- P9: final BN+GELU+resid -> pool atomics ----
  {
    float* scv = &sh.sres[0][0];
    float* shv = &sh.sres[1][0];
    if (t < 64) {
      const float* bns = P.bnsums + 2 * NSHARD * 128;
      float s = 0.f, q = 0.f;
      for (int sd = 0; sd < NSHARD; ++sd) {
        s += bns[sd * 128 + t];
        q += bns[sd * 128 + 64 + t];
      }
      float mu = s * P.inv_n;
      float var = q * P.inv_n - mu * mu;
      float rs = rsqrtf(var + 1e-5f) * P.gam2[t];
      scv[t] = rs;
      shv[t] = P.bet2[t] - mu * rs;
    }
    __syncthreads();
    int total = N * 64;
    for (int idx = blockIdx.x * 256 + t; idx < total; idx += gridDim.x * 256) {
      int c = idx & 63;
      float v = fmaf(P.gat[idx], scv[c], shv[c]);
      float ge = 0.5f * v * (1.f + erff(v * 0.70710678118654752f));
      float val = ge + P.hB[idx];
      atomicAdd(&P.pool[(size_t)P.batch[idx >> 6] * 64 + c], val);
    }
  }
  gsync(P.bar);

  // ---- P10: heads ----
  for (int g = blockIdx.x; g < P.G; g += gridDim.x) {
    if (t < 64) sh.sres[0][t] = P.pool[(size_t)g * 64 + t];
    __syncthreads();
    if (t < 64) {
      float am = 0.f, al = 0.f;
      for (int k = 0; k < 64; ++k) {
        float r = sh.sres[0][k];
        am = fmaf(r, P.Wmu[k * 64 + t], am);
        al = fmaf(r, P.Wlv[k * 64 + t], al);
      }
      P.out[(size_t)g * 64 + t] = am + P.bmu[t];
      P.out[(size_t)P.G * 64 + (size_t)g * 64 + t] = al + P.blv[t];
    }
    __syncthreads();
  }
}

// ---------------- launch ----------------

extern "C" void kernel_launch(void* const* d_in, const int* in_sizes, int n_in,
                              void* d_out, int out_size, void* d_ws, size_t ws_size,
                              hipStream_t stream) {
  const int N = in_sizes[0] / 64;
  const int E = in_sizes[1];
  const int G = out_size / 128;

  char* p = (char*)d_ws;
  auto alloc = [&](size_t bytes) -> void* {
    void* r = (void*)p;
    p += (bytes + 255) & ~(size_t)255;
    return r;
  };
  // zero-init region (one memset: bar + deg + bnsums + pool)
  int*   bar     = (int*)alloc(256);
  int*   deg     = (int*)alloc((size_t)N * 4);
  float* bnsums  = (float*)alloc(3 * NSHARD * 128 * 4);
  float* pool    = (float*)alloc((size_t)G * 64 * 4);
  char*  zend    = p;
  unsigned short* xlb = (unsigned short*)alloc((size_t)N * 256 * 2);
  unsigned short* xrb = (unsigned short*)alloc((size_t)N * 256 * 2);
  float* hA     = (float*)alloc((size_t)N * 64 * 4);
  float* hB     = (float*)alloc((size_t)N * 64 * 4);
  float* gat    = (float*)alloc((size_t)N * 64 * 4);
  int*   rowptr = (int*)alloc((size_t)(N + 1) * 4);
  int*   cursor = (int*)alloc((size_t)N * 4);
  int*   bs     = (int*)alloc(256 * 4);
  int*   colb   = (int*)alloc((size_t)(E + 16) * 4);
  unsigned short* wt = (unsigned short*)alloc(6 * 16384 * 2);

  Params P;
  P.x = (const float*)d_in[0];
  P.esrc = (const int*)d_in[1];
  P.edst = (const int*)d_in[2];
  P.batch = (const int*)d_in[3];
  P.W0 = (const float*)d_in[5];  P.W1 = (const float*)d_in[6];
  P.W2 = (const float*)d_in[11]; P.W3 = (const float*)d_in[12];
  P.W4 = (const float*)d_in[17]; P.W5 = (const float*)d_in[18];
  P.att0 = (const float*)d_in[7];  P.bia0 = (const float*)d_in[8];
  P.gam0 = (const float*)d_in[9];  P.bet0 = (const float*)d_in[10];
  P.att1 = (const float*)d_in[13]; P.bia1 = (const float*)d_in[14];
  P.gam1 = (const float*)d_in[15]; P.bet1 = (const float*)d_in[16];
  P.att2 = (const float*)d_in[19]; P.bia2 = (const float*)d_in[20];
  P.gam2 = (const float*)d_in[21]; P.bet2 = (const float*)d_in[22];
  P.Wmu = (const float*)d_in[23]; P.bmu = (const float*)d_in[24];
  P.Wlv = (const float*)d_in[25]; P.blv = (const float*)d_in[26];
  P.out = (float*)d_out;
  P.wt = wt; P.xlb = xlb; P.xrb = xrb;
  P.hA = hA; P.hB = hB; P.gat = gat; P.bnsums = bnsums; P.pool = pool;
  P.deg = deg; P.rowptr = rowptr; P.cursor = cursor; P.bs = bs; P.colb = colb;
  P.bar = bar;
  P.N = N; P.E = E; P.G = G;
  P.nbN = (N + 255) / 256;
  P.ntiles = (N + 31) / 32;
  P.nbGat = (N + 3) / 4;
  P.inv_n = 1.f / (float)N;

  hipMemsetAsync(bar, 0, (size_t)(zend - (char*)bar), stream);
  k_mega<<<dim3(GRIDB), dim3(256), 0, stream>>>(P);
}

// Round 12
// 499.687 us; speedup vs baseline: 5.0640x; 5.0640x over previous
//
#include <hip/hip_runtime.h>
#include <math.h>

typedef __attribute__((ext_vector_type(8))) short bf16x8;
typedef __attribute__((ext_vector_type(4))) float f32x4;
typedef __attribute__((ext_vector_type(2))) float f32x2;

static __device__ __forceinline__ unsigned short f2bf(float f) {
  unsigned u = __float_as_uint(f);
  unsigned r = (u + 0x7FFF + ((u >> 16) & 1)) >> 16; // RNE
  return (unsigned short)r;
}
static __device__ __forceinline__ float bf2f(unsigned short b) {
  return __uint_as_float(((unsigned)b) << 16);
}

// DPP add: x += lane-permuted x (ctrl must be an immediate)
#define DPP_ADD(x, ctrl) \
  ((x) + __int_as_float(__builtin_amdgcn_update_dpp(0, __float_as_int(x), (ctrl), 0xf, 0xf, false)))

#define NSHARD 64

// ---------------- fused W-prep + degree count ----------------

__global__ __launch_bounds__(256) void k_prep(const float* __restrict__ W0, const float* __restrict__ W1,
                                              const float* __restrict__ W2, const float* __restrict__ W3,
                                              const float* __restrict__ W4, const float* __restrict__ W5,
                                              unsigned short* __restrict__ wt,
                                              const int* __restrict__ edst,
                                              int* __restrict__ deg, int E) {
  if (blockIdx.x < 384) {
    int gid = blockIdx.x * 256 + threadIdx.x; // 6 * 16384
    int m = gid >> 14;
    int r = gid & 16383;
    int k = r >> 8;
    int n = r & 255;
    const float* W = (m == 0) ? W0 : (m == 1) ? W1 : (m == 2) ? W2
                   : (m == 3) ? W3 : (m == 4) ? W4 : W5;
    wt[(size_t)m * 16384 + n * 64 + k] = f2bf(W[k * 256 + n]);
  } else {
    int e = (blockIdx.x - 384) * 256 + threadIdx.x;
    if (e < E) atomicAdd(&deg[edst[e]], 1);
  }
}

// ---------------- parallel scan: per-block scan + redundant block-sum scan ----------------

__global__ __launch_bounds__(256) void k_scan1(const int* __restrict__ deg,
                                               int* __restrict__ part,
                                               int* __restrict__ bs, int N) {
  __shared__ int s[256];
  int gid = blockIdx.x * 256 + threadIdx.x;
  int v = (gid < N) ? deg[gid] : 0;
  s[threadIdx.x] = v;
  __syncthreads();
  for (int off = 1; off < 256; off <<= 1) {
    int t = (threadIdx.x >= off) ? s[threadIdx.x - off] : 0;
    __syncthreads();
    s[threadIdx.x] += t;
    __syncthreads();
  }
  if (gid < N) part[gid] = s[threadIdx.x] - v; // exclusive within block
  if (threadIdx.x == 255) bs[blockIdx.x] = s[255];
}

__global__ __launch_bounds__(256) void k_scanadd(int* __restrict__ rowptr,
                                                 const int* __restrict__ bs,
                                                 int* __restrict__ cursor,
                                                 int* __restrict__ colb,
                                                 int N, int E, int nb) {
  __shared__ int s[256];
  int v = (threadIdx.x < nb) ? bs[threadIdx.x] : 0;
  s[threadIdx.x] = v;
  __syncthreads();
  for (int off = 1; off < 256; off <<= 1) {
    int t = (threadIdx.x >= off) ? s[threadIdx.x - off] : 0;
    __syncthreads();
    s[threadIdx.x] += t;
    __syncthreads();
  }
  __shared__ int boff;
  if (threadIdx.x == blockIdx.x) boff = s[threadIdx.x] - v; // exclusive prefix of this block
  __syncthreads();
  int gid = blockIdx.x * 256 + threadIdx.x;
  if (gid < N) {
    int val = rowptr[gid] + boff;
    rowptr[gid] = val;
    cursor[gid] = val;
  }
  if (gid == 0) rowptr[N] = E;
  if (blockIdx.x == 0 && threadIdx.x < 16) colb[E + threadIdx.x] = 0; // sentinels
}

// ---------------- MFMA dual GEMM + fused BN/GELU/residual producer ----------------
// grid (GX, 2 or 3): y=0 -> Wl -> xlb (and writes hout); y=1 -> Wr -> xrb;
// y=2 (layer0 only) -> CSR fill (independent of the GEMM; completes before gat0).

__global__ __launch_bounds__(256) void k_mm(const float* __restrict__ src,
                                            const float* __restrict__ bnsums,
                                            const float* __restrict__ g,
                                            const float* __restrict__ be,
                                            const float* __restrict__ resid,
                                            float* __restrict__ hout,
                                            const unsigned short* __restrict__ wt,
                                            unsigned short* __restrict__ xlb,
                                            unsigned short* __restrict__ xrb,
                                            const int* __restrict__ esrc,
                                            const int* __restrict__ edst,
                                            int* __restrict__ cursor,
                                            int* __restrict__ colb, int E,
                                            int N, int ntiles, float inv_n) {
  if (blockIdx.y == 2) {
    // CSR fill partition
    for (int e = blockIdx.x * 256 + threadIdx.x; e < E; e += gridDim.x * 256) {
      int p = atomicAdd(&cursor[edst[e]], 1);
      colb[p] = esrc[e] << 9; // byte offset into bf16 rows (256 bf16 = 512 B)
    }
    return;
  }
  __shared__ unsigned short Ah[32][72], Al[32][72];
  __shared__ unsigned short B[256][72];
  __shared__ float stat[128];
  const int t = threadIdx.x;
  const unsigned short* wb = wt + (blockIdx.y ? 16384 : 0);
  unsigned short* dst = blockIdx.y ? xrb : xlb;

#pragma unroll
  for (int j = 0; j < 8; ++j) {
    int cidx = t + 256 * j;
    int n = cidx >> 3, k0 = (cidx & 7) * 8;
    *(bf16x8*)&B[n][k0] = *(const bf16x8*)(wb + (size_t)n * 64 + k0);
  }

  const int wave = t >> 6, lane = t & 63;
  const int rw = (wave & 1) * 16, cw = (wave >> 1) * 128;
  const int m15 = lane & 15, quad = lane >> 4;
  const int arow = t >> 3, ac0 = (t & 7) * 8;

  float scale[8], shift[8];
  if (bnsums) {
    if (t < 128) {
      float a = 0.f;
      for (int sd = 0; sd < NSHARD; ++sd) a += bnsums[sd * 128 + t];
      stat[t] = a;
    }
    __syncthreads();
#pragma unroll
    for (int i = 0; i < 8; ++i) {
      int c = ac0 + i;
      float mu = stat[c] * inv_n;
      float var = stat[64 + c] * inv_n - mu * mu;
      float rs = rsqrtf(var + 1e-5f) * g[c];
      scale[i] = rs;
      shift[i] = be[c] - mu * rs;
    }
  }
  const bool wr_h = (hout != nullptr) && (blockIdx.y == 0);

  for (int tile = blockIdx.x; tile < ntiles; tile += gridDim.x) {
    int r0 = tile * 32;
    {
      int gr = r0 + arow;
      float vs[8] = {0.f, 0.f, 0.f, 0.f, 0.f, 0.f, 0.f, 0.f};
      if (gr < N) {
        float4 v0 = *(const float4*)(src + (size_t)gr * 64 + ac0);
        float4 v1 = *(const float4*)(src + (size_t)gr * 64 + ac0 + 4);
        vs[0] = v0.x; vs[1] = v0.y; vs[2] = v0.z; vs[3] = v0.w;
        vs[4] = v1.x; vs[5] = v1.y; vs[6] = v1.z; vs[7] = v1.w;
        if (bnsums) {
          float rv[8] = {0.f, 0.f, 0.f, 0.f, 0.f, 0.f, 0.f, 0.f};
          if (resid) {
            float4 r0v = *(const float4*)(resid + (size_t)gr * 64 + ac0);
            float4 r1v = *(const float4*)(resid + (size_t)gr * 64 + ac0 + 4);
            rv[0] = r0v.x; rv[1] = r0v.y; rv[2] = r0v.z; rv[3] = r0v.w;
            rv[4] = r1v.x; rv[5] = r1v.y; rv[6] = r1v.z; rv[7] = r1v.w;
          }
#pragma unroll
          for (int i = 0; i < 8; ++i) {
            float v = fmaf(vs[i], scale[i], shift[i]);
            float ge = 0.5f * v * (1.f + erff(v * 0.70710678118654752f));
            vs[i] = ge + rv[i];
          }
          if (wr_h) {
            float4 o0 = {vs[0], vs[1], vs[2], vs[3]};
            float4 o1 = {vs[4], vs[5], vs[6], vs[7]};
            *(float4*)(hout + (size_t)gr * 64 + ac0) = o0;
            *(float4*)(hout + (size_t)gr * 64 + ac0 + 4) = o1;
          }
        }
      }
      bf16x8 hi8, lo8;
#pragma unroll
      for (int i = 0; i < 8; ++i) {
        unsigned short hh = f2bf(vs[i]);
        hi8[i] = (short)hh;
        lo8[i] = (short)f2bf(vs[i] - bf2f(hh));
      }
      *(bf16x8*)&Ah[arow][ac0] = hi8;
      *(bf16x8*)&Al[arow][ac0] = lo8;
    }
    __syncthreads();

    f32x4 acc[8];
#pragma unroll
    for (int s = 0; s < 8; ++s) acc[s] = (f32x4){0.f, 0.f, 0.f, 0.f};
#pragma unroll
    for (int kk = 0; kk < 64; kk += 32) {
      bf16x8 ah = *(const bf16x8*)&Ah[rw + m15][kk + quad * 8];
      bf16x8 al = *(const bf16x8*)&Al[rw + m15][kk + quad * 8];
#pragma unroll
      for (int s = 0; s < 8; ++s) {
        bf16x8 b = *(const bf16x8*)&B[cw + s * 16 + m15][kk + quad * 8];
        acc[s] = __builtin_amdgcn_mfma_f32_16x16x32_bf16(ah, b, acc[s], 0, 0, 0);
        acc[s] = __builtin_amdgcn_mfma_f32_16x16x32_bf16(al, b, acc[s], 0, 0, 0);
      }
    }
#pragma unroll
    for (int s = 0; s < 8; ++s) {
#pragma unroll
      for (int r = 0; r < 4; ++r) {
        int row_g = r0 + rw + quad * 4 + r;
        if (row_g < N)
          dst[(size_t)row_g * 256 + cw + s * 16 + m15] = f2bf(acc[s][r]);
      }
    }
    __syncthreads();
  }
}

// ---------------- GATv2: wave/node, self-score shift, depth-8 pipeline, sharded BN-stats ----

__global__ __launch_bounds__(256) void k_gat(const unsigned short* __restrict__ xlb,
                                             const unsigned short* __restrict__ xrb,
                                             const float* __restrict__ att,
                                             const float* __restrict__ bias,
                                             const int* __restrict__ rowptr,
                                             const int* __restrict__ colb,
                                             float* __restrict__ out,
                                             float* __restrict__ bnsums, int N) {
  __shared__ float sres[4][64];
  const int lane = threadIdx.x & 63;
  const int wv = threadIdx.x >> 6;
  const int node0 = blockIdx.x * 4 + wv;
  const bool valid = node0 < N;
  const int node = __builtin_amdgcn_readfirstlane(valid ? node0 : 0); // wave-uniform
  const int beg = rowptr[node];
  const int end = valid ? rowptr[node + 1] : beg;

  const char* base = (const char*)xlb + (size_t)lane * 8;
  int o0 = colb[beg], o1 = colb[beg + 1], o2 = colb[beg + 2], o3 = colb[beg + 3];
  uint2 vbs = *(const uint2*)(base + (size_t)(unsigned)(node << 9));
  uint2 d0 = *(const uint2*)(base + (size_t)(unsigned)o0);
  uint2 d1 = *(const uint2*)(base + (size_t)(unsigned)o1);
  uint2 d2 = *(const uint2*)(base + (size_t)(unsigned)o2);
  uint2 d3 = *(const uint2*)(base + (size_t)(unsigned)o3);
  int p0 = colb[beg + 4], p1 = colb[beg + 5], p2 = colb[beg + 6], p3 = colb[beg + 7];
  uint2 t0 = *(const uint2*)(base + (size_t)(unsigned)p0);
  uint2 t1 = *(const uint2*)(base + (size_t)(unsigned)p1);
  uint2 t2 = *(const uint2*)(base + (size_t)(unsigned)p2);
  uint2 t3 = *(const uint2*)(base + (size_t)(unsigned)p3);
  int f0 = colb[beg + 8], f1 = colb[beg + 9], f2 = colb[beg + 10], f3 = colb[beg + 11];

  float4 a4 = *(const float4*)(att + lane * 4);
  const float LOG2E = 1.4426950408889634f;
  const f32x2 a01 = {a4.x * LOG2E, a4.y * LOG2E};
  const f32x2 a23 = {a4.z * LOG2E, a4.w * LOG2E};
  const f32x2 c02 = {0.2f, 0.2f};
  uint2 xru = *(const uint2*)((const char*)xrb + ((size_t)(unsigned)(node << 9)) + lane * 8);
  const f32x2 xr01 = {__uint_as_float(xru.x << 16), __uint_as_float(xru.x & 0xFFFF0000u)};
  const f32x2 xr23 = {__uint_as_float(xru.y << 16), __uint_as_float(xru.y & 0xFFFF0000u)};

  f32x2 sv01 = {__uint_as_float(vbs.x << 16), __uint_as_float(vbs.x & 0xFFFF0000u)};
  f32x2 sv23 = {__uint_as_float(vbs.y << 16), __uint_as_float(vbs.y & 0xFFFF0000u)};
  float m;
  {
    f32x2 s01 = sv01 + xr01;
    f32x2 s23 = sv23 + xr23;
    s01 = __builtin_elementwise_max(s01, s01 * c02);
    s23 = __builtin_elementwise_max(s23, s23 * c02);
    f32x2 q = __builtin_elementwise_fma(s23, a23, s01 * a01);
    float p = q.x + q.y;
    p = DPP_ADD(p, 0xB1);
    p = DPP_ADD(p, 0x4E);
    p = DPP_ADD(p, 0x124);
    p = DPP_ADD(p, 0x128);
    m = p;
  }
  float lsum = 1.f;
  f32x2 o01 = sv01, o23 = sv23;

  auto proc = [&](uint2 vb, bool ok) {
    f32x2 v01 = {__uint_as_float(vb.x << 16), __uint_as_float(vb.x & 0xFFFF0000u)};
    f32x2 v23 = {__uint_as_float(vb.y << 16), __uint_as_float(vb.y & 0xFFFF0000u)};
    f32x2 s01 = v01 + xr01;
    f32x2 s23 = v23 + xr23;
    s01 = __builtin_elementwise_max(s01, s01 * c02);
    s23 = __builtin_elementwise_max(s23, s23 * c02);
    f32x2 q = __builtin_elementwise_fma(s23, a23, s01 * a01);
    float p = q.x + q.y;
    p = DPP_ADD(p, 0xB1);
    p = DPP_ADD(p, 0x4E);
    p = DPP_ADD(p, 0x124);
    p = DPP_ADD(p, 0x128);
    float w = __builtin_amdgcn_exp2f(fminf(p - m, 126.f));
    w = ok ? w : 0.f;
    lsum += w;
    f32x2 w2 = {w, w};
    o01 = __builtin_elementwise_fma(w2, v01, o01);
    o23 = __builtin_elementwise_fma(w2, v23, o23);
  };

  for (int e = beg; e < end; e += 4) {
    uint2 u0 = *(const uint2*)(base + (size_t)(unsigned)f0);
    uint2 u1 = *(const uint2*)(base + (size_t)(unsigned)f1);
    uint2 u2 = *(const uint2*)(base + (size_t)(unsigned)f2);
    uint2 u3 = *(const uint2*)(base + (size_t)(unsigned)f3);
    f0 = colb[e + 12]; f1 = colb[e + 13]; f2 = colb[e + 14]; f3 = colb[e + 15];
    proc(d0, true);
    proc(d1, e + 1 < end);
    proc(d2, e + 2 < end);
    proc(d3, e + 3 < end);
    d0 = t0; d1 = t1; d2 = t2; d3 = t3;
    t0 = u0; t1 = u1; t2 = u2; t3 = u3;
  }

  float inv = __builtin_amdgcn_rcpf(lsum);
  float rx = o01.x * inv, ry = o01.y * inv, rz = o23.x * inv, rw2 = o23.y * inv;
  rx += __shfl_xor(rx, 16, 64); rx += __shfl_xor(rx, 32, 64);
  ry += __shfl_xor(ry, 16, 64); ry += __shfl_xor(ry, 32, 64);
  rz += __shfl_xor(rz, 16, 64); rz += __shfl_xor(rz, 32, 64);
  rw2 += __shfl_xor(rw2, 16, 64); rw2 += __shfl_xor(rw2, 32, 64);
  if (lane < 16) {
    float4 res = {0.f, 0.f, 0.f, 0.f};
    if (valid) {
      float4 b4 = *(const float4*)(bias + lane * 4);
      res.x = 0.25f * rx + b4.x;
      res.y = 0.25f * ry + b4.y;
      res.z = 0.25f * rz + b4.z;
      res.w = 0.25f * rw2 + b4.w;
      *(float4*)(out + (size_t)node * 64 + lane * 4) = res;
    }
    *(float4*)&sres[wv][lane * 4] = res;
  }
  __syncthreads();
  if (threadIdx.x < 64) {
    int c = threadIdx.x;
    float s0 = sres[0][c], s1 = sres[1][c], s2 = sres[2][c], s3 = sres[3][c];
    float* bs = bnsums + (size_t)(blockIdx.x & (NSHARD - 1)) * 128;
    atomicAdd(&bs[c], s0 + s1 + s2 + s3);
    atomicAdd(&bs[64 + c], s0 * s0 + s1 * s1 + s2 * s2 + s3 * s3);
  }
}

// ---------------- final: collapse shards -> BN+GELU+residual -> pool atomics ----------------

__global__ __launch_bounds__(256) void k_bn_pool(const float* __restrict__ gat,
                                                 const float* __restrict__ bnsums,
                                                 const float* __restrict__ g,
                                                 const float* __restrict__ be,
                                                 const float* __restrict__ resid,
                                                 const int* __restrict__ batch,
                                                 float* __restrict__ pool,
                                                 int total, float inv_n) {
  __shared__ float sc[64], sh[64];
  if (threadIdx.x < 64) {
    int c = threadIdx.x;
    float s = 0.f, q = 0.f;
    for (int sd = 0; sd < NSHARD; ++sd) {
      s += bnsums[sd * 128 + c];
      q += bnsums[sd * 128 + 64 + c];
    }
    float mu = s * inv_n;
    float var = q * inv_n - mu * mu;
    float rs = rsqrtf(var + 1e-5f) * g[c];
    sc[c] = rs;
    sh[c] = be[c] - mu * rs;
  }
  __syncthreads();
  for (int idx = blockIdx.x * 256 + threadIdx.x; idx < total; idx += gridDim.x * 256) {
    int c = idx & 63;
    float v = fmaf(gat[idx], sc[c], sh[c]);
    float ge = 0.5f * v * (1.f + erff(v * 0.70710678118654752f));
    float val = ge + resid[idx];
    atomicAdd(&pool[(size_t)batch[idx >> 6] * 64 + c], val);
  }
}

// ---------------- heads ----------------

__global__ void k_head(const float* __restrict__ pool, const float* __restrict__ Wmu,
                       const float* __restrict__ bmu, const float* __restrict__ Wlv,
                       const float* __restrict__ blv, float* __restrict__ out, int G) {
  int g = blockIdx.x;
  int c = threadIdx.x; // 64 threads
  __shared__ float row[64];
  row[c] = pool[(size_t)g * 64 + c];
  __syncthreads();
  float am = 0.f, al = 0.f;
  for (int k = 0; k < 64; ++k) {
    float r = row[k];
    am = fmaf(r, Wmu[k * 64 + c], am);
    al = fmaf(r, Wlv[k * 64 + c], al);
  }
  out[(size_t)g * 64 + c] = am + bmu[c];
  out[(size_t)G * 64 + (size_t)g * 64 + c] = al + blv[c];
}

// ---------------- launch ----------------

extern "C" void kernel_launch(void* const* d_in, const int* in_sizes, int n_in,
                              void* d_out, int out_size, void* d_ws, size_t ws_size,
                              hipStream_t stream) {
  const float* x    = (const float*)d_in[0];
  const int* esrc   = (const int*)d_in[1];
  const int* edst   = (const int*)d_in[2];
  const int* batch  = (const int*)d_in[3];
  const float* Wl[3]  = {(const float*)d_in[5],  (const float*)d_in[11], (const float*)d_in[17]};
  const float* Wr[3]  = {(const float*)d_in[6],  (const float*)d_in[12], (const float*)d_in[18]};
  const float* att[3] = {(const float*)d_in[7],  (const float*)d_in[13], (const float*)d_in[19]};
  const float* bia[3] = {(const float*)d_in[8],  (const float*)d_in[14], (const float*)d_in[20]};
  const float* gam[3] = {(const float*)d_in[9],  (const float*)d_in[15], (const float*)d_in[21]};
  const float* bet[3] = {(const float*)d_in[10], (const float*)d_in[16], (const float*)d_in[22]};
  const float* Wmu = (const float*)d_in[23];
  const float* bmu = (const float*)d_in[24];
  const float* Wlv = (const float*)d_in[25];
  const float* blv = (const float*)d_in[26];
  float* out = (float*)d_out;

  const int N = in_sizes[0] / 64;
  const int E = in_sizes[1];
  const int G = out_size / 128;

  char* p = (char*)d_ws;
  auto alloc = [&](size_t bytes) -> void* {
    void* r = (void*)p;
    p += (bytes + 255) & ~(size_t)255;
    return r;
  };
  // zero-init region first (one memset covers deg + bnsums + pool)
  int*   deg     = (int*)alloc((size_t)N * 4);
  float* bnsums  = (float*)alloc(3 * NSHARD * 128 * 4);
  float* pool    = (float*)alloc((size_t)G * 64 * 4);
  char*  zend    = p;
  unsigned short* xlb = (unsigned short*)alloc((size_t)N * 256 * 2);
  unsigned short* xrb = (unsigned short*)alloc((size_t)N * 256 * 2);
  float* hA     = (float*)alloc((size_t)N * 64 * 4);
  float* hB     = (float*)alloc((size_t)N * 64 * 4);
  float* gat    = (float*)alloc((size_t)N * 64 * 4);
  int*   rowptr = (int*)alloc((size_t)(N + 1) * 4);
  int*   cursor = (int*)alloc((size_t)N * 4);
  int*   bs     = (int*)alloc(256 * 4);
  int*   colb   = (int*)alloc((size_t)(E + 16) * 4);
  unsigned short* wt = (unsigned short*)alloc(6 * 16384 * 2);

  const int nbN   = (N + 255) / 256;
  const int nbE   = (E + 255) / 256;
  const int nbGat = (N + 3) / 4;
  const int ntiles = (N + 31) / 32;
  const float inv_n = 1.f / (float)N;

  hipMemsetAsync(deg, 0, (size_t)(zend - (char*)deg), stream);

  // ---- fused W-prep + degree; parallel scan ----
  k_prep<<<384 + nbE, 256, 0, stream>>>(Wl[0], Wr[0], Wl[1], Wr[1], Wl[2], Wr[2], wt,
                                        edst, deg, E);
  k_scan1<<<nbN, 256, 0, stream>>>(deg, rowptr, bs, N);
  k_scanadd<<<nbN, 256, 0, stream>>>(rowptr, bs, cursor, colb, N, E, nbN);

  float* bns0 = bnsums;
  float* bns1 = bnsums + NSHARD * 128;
  float* bns2 = bnsums + 2 * NSHARD * 128;

  // ---- layer 0 (y=2 partition does CSR fill concurrently) ----
  k_mm<<<dim3(384, 3), 256, 0, stream>>>(x, nullptr, nullptr, nullptr, nullptr, nullptr,
                                         wt, xlb, xrb, esrc, edst, cursor, colb, E,
                                         N, ntiles, inv_n);
  k_gat<<<nbGat, 256, 0, stream>>>(xlb, xrb, att[0], bia[0], rowptr, colb, gat, bns0, N);
  // ---- layer 1 (k_mm applies h0 = gelu(bn0(gat0))) ----
  k_mm<<<dim3(384, 2), 256, 0, stream>>>(gat, bns0, gam[0], bet[0], nullptr, hA,
                                         wt + 2 * 16384, xlb, xrb, nullptr, nullptr,
                                         nullptr, nullptr, 0, N, ntiles, inv_n);
  k_gat<<<nbGat, 256, 0, stream>>>(xlb, xrb, att[1], bia[1], rowptr, colb, gat, bns1, N);
  // ---- layer 2 (k_mm applies h1 = gelu(bn1(gat1)) + h0) ----
  k_mm<<<dim3(384, 2), 256, 0, stream>>>(gat, bns1, gam[1], bet[1], hA, hB,
                                         wt + 4 * 16384, xlb, xrb, nullptr, nullptr,
                                         nullptr, nullptr, 0, N, ntiles, inv_n);
  k_gat<<<nbGat, 256, 0, stream>>>(xlb, xrb, att[2], bia[2], rowptr, colb, gat, bns2, N);
  // ---- final: h2 = gelu(bn2(gat2)) + h1 -> pool ----
  k_bn_pool<<<256, 256, 0, stream>>>(gat, bns2, gam[2], bet[2], hB, batch, pool,
                                     N * 64, inv_n);
  k_head<<<G, 64, 0, stream>>>(pool, Wmu, bmu, Wlv, blv, out, G);
}